// Round 2
// baseline (28141.318 us; speedup 1.0000x reference)
//
#include <hip/hip_runtime.h>
#include <math.h>

// CustomGRU: B=64, S=512, F=512, H=1024. ALL I/O IS FP32 (per reference dtypes).
// Round 1: fp32 I/O + split-bf16 (hi+lo) MFMA compute.
//   pack_w : fp32 Wih/Whh -> Wt_hi/Wt_lo bf16 [4096][1536], K-major packed:
//     rows [0,1024)=z (k<512 from Wih, k>=512 from Whh), [1024,2048)=r,
//     [2048,3072)=gx_e (k<512 only), [3072,4096)=gh_e (k>=512 only).
//   pack_x : fp32 x -> x_hi/x_lo bf16.
//   gru_step x512: grid 64 wg x 256thr; wg = 16 hidden cols, wave = 16-batch
//     tile. 4 accumulators (z,r,gx_e,gh_e); each product uses 3 MFMAs
//     (hi*HI + hi*LO + lo*HI) for ~2^-17 relative GEMM error. h state fp32,
//     double-buffered bf16 hi/lo copies for next step's A-operand.

#define B_   64
#define S_   512
#define F_   512
#define H_   1024
#define KTOT 1536
#define NG   4096

typedef short short8 __attribute__((ext_vector_type(8)));
typedef float floatx4 __attribute__((ext_vector_type(4)));

__device__ __forceinline__ float bf2f(unsigned short u) {
    union { unsigned int i; float f; } v; v.i = ((unsigned int)u) << 16; return v.f;
}
__device__ __forceinline__ unsigned short f2bf(float f) {
    union { float f; unsigned int i; } v; v.f = f;
    unsigned int x = v.i;
    x += 0x7fffu + ((x >> 16) & 1u);            // round-to-nearest-even
    return (unsigned short)(x >> 16);
}
__device__ __forceinline__ void split2(float v, unsigned short& hi, unsigned short& lo) {
    hi = f2bf(v);
    lo = f2bf(v - bf2f(hi));
}

__global__ void pack_w(const float* __restrict__ Wih,
                       const float* __restrict__ Whh,
                       unsigned short* __restrict__ Whi,
                       unsigned short* __restrict__ Wlo) {
    int idx = blockIdx.x * 256 + threadIdx.x;   // < NG*KTOT
    int n = idx / KTOT;
    int k = idx - n * KTOT;
    int g = n >> 10, j = n & 1023;
    float v = 0.f;
    if (g <= 1) {
        int c = g * 1024 + j;
        v = (k < F_) ? Wih[k * 3072 + c] : Whh[(k - F_) * 3072 + c];
    } else if (g == 2) {
        if (k < F_) v = Wih[k * 3072 + (2048 + j)];
    } else {
        if (k >= F_) v = Whh[(k - F_) * 3072 + (2048 + j)];
    }
    unsigned short hi, lo; split2(v, hi, lo);
    Whi[idx] = hi; Wlo[idx] = lo;
}

__global__ void pack_x(const float* __restrict__ x,
                       unsigned short* __restrict__ xhi,
                       unsigned short* __restrict__ xlo) {
    int idx = blockIdx.x * 256 + threadIdx.x;   // < B_*S_*F_
    unsigned short hi, lo; split2(x[idx], hi, lo);
    xhi[idx] = hi; xlo[idx] = lo;
}

#define MFMA3(acc, ahi, alo, bp_hi, bp_lo)                                      \
    do {                                                                        \
        short8 _bh = *(const short8*)(bp_hi);                                   \
        short8 _bl = *(const short8*)(bp_lo);                                   \
        acc = __builtin_amdgcn_mfma_f32_16x16x32_bf16(ahi, _bh, acc, 0, 0, 0);  \
        acc = __builtin_amdgcn_mfma_f32_16x16x32_bf16(ahi, _bl, acc, 0, 0, 0);  \
        acc = __builtin_amdgcn_mfma_f32_16x16x32_bf16(alo, _bh, acc, 0, 0, 0);  \
    } while (0)

__global__ __launch_bounds__(256) void gru_step(
    const unsigned short* __restrict__ xhi,
    const unsigned short* __restrict__ xlo,
    const unsigned short* __restrict__ Whi,
    const unsigned short* __restrict__ Wlo,
    const float* __restrict__ bias,
    const float* __restrict__ hf_in,
    float* __restrict__ hf_out,
    const unsigned short* __restrict__ hhi_in,
    const unsigned short* __restrict__ hlo_in,
    unsigned short* __restrict__ hhi_out,
    unsigned short* __restrict__ hlo_out,
    float* __restrict__ out,
    int t)
{
    const int j0 = blockIdx.x * 16;               // hidden-col tile (64 wgs)
    const int wave = threadIdx.x >> 6;            // 4 waves: batch tiles
    const int m0 = wave * 16;
    const int lane = threadIdx.x & 63;
    const int l15 = lane & 15, quad = lane >> 4;

    floatx4 accZ = {0.f, 0.f, 0.f, 0.f};
    floatx4 accR = accZ, accE = accZ, accH = accZ;

    // A-operand: lane holds A[m=lane&15][k=quad*8+j]
    const size_t arow = (size_t)(m0 + l15);
    const unsigned short* axh = xhi + (arow * S_ + t) * F_ + quad * 8;
    const unsigned short* axl = xlo + (arow * S_ + t) * F_ + quad * 8;
    const unsigned short* ahh = hhi_in + arow * H_ + quad * 8;
    const unsigned short* ahl = hlo_in + arow * H_ + quad * 8;
    // B-operand: lane holds B[n=lane&15][k=quad*8+j]; Wt rows K-major
    const size_t brow = (size_t)(j0 + l15) * KTOT + quad * 8;
    const unsigned short* wzh = Whi + brow;
    const unsigned short* wzl = Wlo + brow;
    const size_t OR = (size_t)1024 * KTOT;        // gate-row stride

    // k in [0,512): x part -> z, r, gx_e
    #pragma unroll 2
    for (int ks = 0; ks < 16; ++ks) {
        short8 ahi = *(const short8*)(axh + ks * 32);
        short8 alo = *(const short8*)(axl + ks * 32);
        MFMA3(accZ, ahi, alo, wzh + ks * 32,          wzl + ks * 32);
        MFMA3(accR, ahi, alo, wzh + OR + ks * 32,     wzl + OR + ks * 32);
        MFMA3(accE, ahi, alo, wzh + 2 * OR + ks * 32, wzl + 2 * OR + ks * 32);
    }
    // k in [512,1536): h part -> z, r, gh_e
    #pragma unroll 2
    for (int ks = 0; ks < 32; ++ks) {
        short8 ahi = *(const short8*)(ahh + ks * 32);
        short8 alo = *(const short8*)(ahl + ks * 32);
        MFMA3(accZ, ahi, alo, wzh + 512 + ks * 32,          wzl + 512 + ks * 32);
        MFMA3(accR, ahi, alo, wzh + OR + 512 + ks * 32,     wzl + OR + 512 + ks * 32);
        MFMA3(accH, ahi, alo, wzh + 3 * OR + 512 + ks * 32, wzl + 3 * OR + 512 + ks * 32);
    }

    // Epilogue: C/D layout row(batch)=quad*4+reg, col(hidden)=lane&15
    const int j = j0 + l15;
    const float bZ = bias[j];
    const float bR = bias[1024 + j];
    const float bE = bias[2048 + j];
    #pragma unroll
    for (int r = 0; r < 4; ++r) {
        const int b = m0 + quad * 4 + r;
        float z   = 1.f / (1.f + __expf(-(accZ[r] + bZ)));
        float rr  = 1.f / (1.f + __expf(-(accR[r] + bR)));
        float eta = tanhf(accE[r] + bE + rr * tanhf(accH[r]));
        float ho  = hf_in[b * H_ + j];
        float hn  = z * ho + (1.f - z) * eta;
        hf_out[b * H_ + j] = hn;
        unsigned short hi, lo; split2(hn, hi, lo);
        hhi_out[b * H_ + j] = hi;
        hlo_out[b * H_ + j] = lo;
        out[(size_t)b * (S_ * H_) + (size_t)t * H_ + j] = hn;
    }
}

__global__ void write_hlast(const float* __restrict__ hf,
                            float* __restrict__ dst) {
    int i = blockIdx.x * 256 + threadIdx.x;       // < B_*H_
    dst[i] = hf[i];
}

extern "C" void kernel_launch(void* const* d_in, const int* in_sizes, int n_in,
                              void* d_out, int out_size, void* d_ws, size_t ws_size,
                              hipStream_t stream) {
    const float* x    = (const float*)d_in[0];    // [B,S,F]
    const float* Wih  = (const float*)d_in[1];    // [F,3H]
    const float* Whh  = (const float*)d_in[2];    // [H,3H]
    const float* bias = (const float*)d_in[3];    // [3H]
    float* out = (float*)d_out;                   // [B,S,H] ++ [B,H], fp32

    char* ws = (char*)d_ws;
    unsigned short* Whi = (unsigned short*)ws; ws += (size_t)NG * KTOT * 2;   // 12.6 MB
    unsigned short* Wlo = (unsigned short*)ws; ws += (size_t)NG * KTOT * 2;   // 12.6 MB
    unsigned short* xhi = (unsigned short*)ws; ws += (size_t)B_ * S_ * F_ * 2; // 33.6 MB
    unsigned short* xlo = (unsigned short*)ws; ws += (size_t)B_ * S_ * F_ * 2; // 33.6 MB
    float* hf0 = (float*)ws;           ws += (size_t)B_ * H_ * 4;
    float* hf1 = (float*)ws;           ws += (size_t)B_ * H_ * 4;
    unsigned short* hhi0 = (unsigned short*)ws; ws += (size_t)B_ * H_ * 2;
    unsigned short* hhi1 = (unsigned short*)ws; ws += (size_t)B_ * H_ * 2;
    unsigned short* hlo0 = (unsigned short*)ws; ws += (size_t)B_ * H_ * 2;
    unsigned short* hlo1 = (unsigned short*)ws; ws += (size_t)B_ * H_ * 2;

    hipMemsetAsync(hf0,  0, (size_t)B_ * H_ * 4, stream);
    hipMemsetAsync(hhi0, 0, (size_t)B_ * H_ * 2, stream);
    hipMemsetAsync(hlo0, 0, (size_t)B_ * H_ * 2, stream);

    pack_w<<<(NG * KTOT) / 256, 256, 0, stream>>>(Wih, Whh, Whi, Wlo);
    pack_x<<<(B_ * S_ * F_) / 256, 256, 0, stream>>>(x, xhi, xlo);

    for (int t = 0; t < S_; ++t) {
        const int p = t & 1;
        gru_step<<<64, 256, 0, stream>>>(
            xhi, xlo, Whi, Wlo, bias,
            p ? hf1 : hf0,  p ? hf0 : hf1,
            p ? hhi1 : hhi0, p ? hlo1 : hlo0,
            p ? hhi0 : hhi1, p ? hlo0 : hlo1,
            out, t);
    }
    // final h is in buffer parity (S_ & 1)==0 -> hf0
    write_hlast<<<(B_ * H_) / 256, 256, 0, stream>>>(hf0, out + (size_t)B_ * S_ * H_);
}